// Round 3
// baseline (1518.908 us; speedup 1.0000x reference)
//
#include <hip/hip_runtime.h>

// RNN scan: h_{t+1} = 0.8*h_t + 0.2*(relu(h_t @ W_rec^T + b_rec + inp_t) + rn_t)
// 128 chains -> 128 blocks x 1024 threads. Thread (n, half) owns HALF of row n
// of W_rec (256 cols) in fp16; the two halves combine through LDS each step.
//
// R6 THEORY: R3-R5 proved the compiler will not grant >128 VGPRs for this
// kernel no matter what (waves_per_eu(2,2), amdgpu_num_vgpr(256),
// launch_bounds(512,2)+122KB LDS all -> VGPR_Count=128). R5's VALUBusy(40%)
// x dur equals the clean VALU issue floor -> the executed instruction stream
// is already ideal; the other 60% is spill/stream stall (160 pinned W regs
// vs 128 budget -> scratch spills, L2-resident, FETCH-invisible).
// FIX: design FOR the 128 budget. 1024 threads, half-row per thread:
//   32 groups of 8 cols per thread, split:
//     groups  0..19 -> 20 NAMED uint4 SSA values (80 VGPRs)  <- fits budget
//     groups 20..28 -> LDS ltail[9][1024] uint4 (147456 B, LDS max)
//     groups 29..31 -> fp16 image in d_ws, streamed from L2 (48 B/thr/step)
//   zero spills, minimal streaming, 4 waves/SIMD (2x latency hiding).
// Per-step combine: half=1 writes its partial to pbuf, half=0 adds, updates
// h, writes hbuf. Costs one extra __syncthreads (~+60us total) but removes
// the ~700us stall tax.
// PREDICT: VALUBusy -> 70-85%, dur -> 550-750 us, LDS_Block_Size ~151552.
//
// h broadcast: EVERY wave's lane g holds h-group (32*half + g) via one
// ds_read_b128 (lanes 32-63 duplicate 0-31 = same-address broadcast, free);
// v_readlane with constant lane index feeds v_dot2_f32_f16's SGPR operand.

#define B_  128
#define T_  512
#define N_  512
#define IN_ 6
#define TPB 1024

#define HREG 20                      // groups in VGPRs  (half-cols 0..160)
#define HLDS 9                       // groups in LDS    (half-cols 160..232)
#define HWS  3                       // groups from d_ws (half-cols 232..256)
#define LDS_C0 (8 * HREG)            // 160
#define WS_C0  (8 * (HREG + HLDS))   // 232

typedef _Float16 half2_t __attribute__((ext_vector_type(2)));

#if __has_builtin(__builtin_amdgcn_fdot2)
#define HAVE_FDOT2 1
#else
#define HAVE_FDOT2 0
#endif

__device__ __forceinline__ float dot2_acc(half2_t a, half2_t b, float c) {
#if HAVE_FDOT2
    return __builtin_amdgcn_fdot2(a, b, c, false);
#else
    c = fmaf((float)a[0], (float)b[0], c);
    c = fmaf((float)a[1], (float)b[1], c);
    return c;
#endif
}

__device__ __forceinline__ half2_t h2bits(unsigned s) {
    union { unsigned u; half2_t h; } cv; cv.u = s; return cv.h;
}

// 8 consecutive fp32 -> 8 packed fp16 in a uint4
__device__ __forceinline__ uint4 pack8(const float* __restrict__ p) {
    const float4 f0 = ((const float4*)p)[0];
    const float4 f1 = ((const float4*)p)[1];
    union { unsigned u[4]; half2_t h[4]; } cv;
    cv.h[0] = half2_t{(_Float16)f0.x, (_Float16)f0.y};
    cv.h[1] = half2_t{(_Float16)f0.z, (_Float16)f0.w};
    cv.h[2] = half2_t{(_Float16)f1.x, (_Float16)f1.y};
    cv.h[3] = half2_t{(_Float16)f1.z, (_Float16)f1.w};
    return uint4{cv.u[0], cv.u[1], cv.u[2], cv.u[3]};
}

// opaque redefinition: blocks rematerialization of the producing load
#define KEEP4(v) asm volatile("" : "+v"((v).x), "+v"((v).y), "+v"((v).z), "+v"((v).w))

// ---- prep: W_rec tail cols -> fp16 image, layout [HWS][TPB] uint4 ----
// index tid = k*TPB + tt; tt -> (n = tt&511, half = tt>>9)
__global__ void prep_tail_kernel(const float* __restrict__ Wrec,
                                 uint4* __restrict__ ws) {
    int tid = blockIdx.x * blockDim.x + threadIdx.x;
    if (tid >= HWS * TPB) return;
    int k = tid >> 10, tt = tid & (TPB - 1);
    int n = tt & (N_ - 1), half = tt >> 9;
    ws[tid] = pack8(Wrec + (size_t)n * N_ + 256 * half + WS_C0 + 8 * k);
}

template <bool USE_WS>
__device__ __forceinline__ uint4 gload(const uint4* __restrict__ wsn,
                                       const float* __restrict__ wrow_ws, int k) {
    if constexpr (USE_WS) return wsn[k * TPB];
    else return pack8(wrow_ws + 8 * k);
}

// one 8-col group: 4 readlane-broadcast h pairs dotted into 4 accumulators
#define DOTG(W, G) do {                                                                    \
    a0 = dot2_acc(h2bits((W).x), h2bits((unsigned)__builtin_amdgcn_readlane(hx,(G))), a0); \
    a1 = dot2_acc(h2bits((W).y), h2bits((unsigned)__builtin_amdgcn_readlane(hy,(G))), a1); \
    a2 = dot2_acc(h2bits((W).z), h2bits((unsigned)__builtin_amdgcn_readlane(hz,(G))), a2); \
    a3 = dot2_acc(h2bits((W).w), h2bits((unsigned)__builtin_amdgcn_readlane(hw,(G))), a3); \
} while (0)

template <bool USE_WS>
__global__ __launch_bounds__(TPB)
void rnn_scan_kernel(
    const float* __restrict__ u,     // [B,T,IN]
    const float* __restrict__ unz,   // [B,T,IN]
    const float* __restrict__ rnz,   // [B,T,N]
    const float* __restrict__ Wrec,  // [N,N]
    const float* __restrict__ brec,  // [N]
    const float* __restrict__ Win,   // [N,IN]
    const uint4* __restrict__ ws,    // fp16 tail image [HWS][TPB]
    float* __restrict__ out)         // [B,T,N]
{
    const int b    = blockIdx.x;
    const int tid  = threadIdx.x;
    const int n    = tid & (N_ - 1);
    const int half = tid >> 9;           // 0: cols 0..255, 1: cols 256..511
    const int lane = tid & 63;
    const int hvidx = (half << 5) | (lane & 31);

    __shared__ uint4 ltail[HLDS][TPB];               // 147456 B
    __shared__ __align__(16) _Float16 hbuf[2][N_];   // 2048 B
    __shared__ float pbuf[N_];                       // 2048 B

    const float* wrow = Wrec + (size_t)n * N_ + 256 * half;

    // ---- one-time: groups 0..19 as 20 NAMED uint4 (80 VGPRs) ----
    uint4 w0  = pack8(wrow +   0); uint4 w1  = pack8(wrow +   8); uint4 w2  = pack8(wrow +  16); uint4 w3  = pack8(wrow +  24);
    uint4 w4  = pack8(wrow +  32); uint4 w5  = pack8(wrow +  40); uint4 w6  = pack8(wrow +  48); uint4 w7  = pack8(wrow +  56);
    uint4 w8  = pack8(wrow +  64); uint4 w9  = pack8(wrow +  72); uint4 w10 = pack8(wrow +  80); uint4 w11 = pack8(wrow +  88);
    uint4 w12 = pack8(wrow +  96); uint4 w13 = pack8(wrow + 104); uint4 w14 = pack8(wrow + 112); uint4 w15 = pack8(wrow + 120);
    uint4 w16 = pack8(wrow + 128); uint4 w17 = pack8(wrow + 136); uint4 w18 = pack8(wrow + 144); uint4 w19 = pack8(wrow + 152);

    KEEP4(w0);  KEEP4(w1);  KEEP4(w2);  KEEP4(w3);  KEEP4(w4);
    KEEP4(w5);  KEEP4(w6);  KEEP4(w7);  KEEP4(w8);  KEEP4(w9);
    KEEP4(w10); KEEP4(w11); KEEP4(w12); KEEP4(w13); KEEP4(w14);
    KEEP4(w15); KEEP4(w16); KEEP4(w17); KEEP4(w18); KEEP4(w19);

    // ---- one-time: groups 20..28 into LDS ----
#pragma unroll
    for (int j = 0; j < HLDS; ++j)
        ltail[j][tid] = pack8(wrow + LDS_C0 + 8 * j);

    const uint4* wsn = ws + tid;
    const float* wrow_ws = wrow + WS_C0;

    // half0-only persistent state
    float win0 = 0, win1 = 0, win2 = 0, win3 = 0, win4 = 0, win5 = 0, br = 0;
    float inp_c = 0, rn_c = 0, h = 0.0f;
    float* ob = out + (size_t)b * T_ * N_;
    const float* rb = rnz + (size_t)b * T_ * N_;
    const float2* ubp = (const float2*)(u   + (size_t)b * T_ * IN_);
    const float2* nbp = (const float2*)(unz + (size_t)b * T_ * IN_);
    const float NS = 0.6324555320336759f;  // sqrt(2/alpha * sigma^2)

    if (!half) {
        win0 = Win[n * IN_ + 0]; win1 = Win[n * IN_ + 1]; win2 = Win[n * IN_ + 2];
        win3 = Win[n * IN_ + 3]; win4 = Win[n * IN_ + 4]; win5 = Win[n * IN_ + 5];
        br = brec[n];
        // inp for t=0
        float2 cu0 = ubp[0], cu1 = ubp[1], cu2 = ubp[2];
        float2 cn0 = nbp[0], cn1 = nbp[1], cn2 = nbp[2];
        inp_c = br;
        inp_c = fmaf(win0, fmaf(NS, cn0.x, cu0.x), inp_c);
        inp_c = fmaf(win1, fmaf(NS, cn0.y, cu0.y), inp_c);
        inp_c = fmaf(win2, fmaf(NS, cn1.x, cu1.x), inp_c);
        inp_c = fmaf(win3, fmaf(NS, cn1.y, cu1.y), inp_c);
        inp_c = fmaf(win4, fmaf(NS, cn2.x, cu2.x), inp_c);
        inp_c = fmaf(win5, fmaf(NS, cn2.y, cu2.y), inp_c);
        rn_c = rb[n];
        hbuf[0][n] = (_Float16)0.0f;
    }
    __syncthreads();

#pragma unroll 1
    for (int t = 0; t < T_ - 1; ++t) {
        if (!half) ob[(size_t)t * N_ + n] = h;   // states[t] (t=0: zeros)

        // every wave: lane g holds h-group (32*half + g); lanes 32-63 dup 0-31
        const uint4 hv = ((const uint4*)hbuf[t & 1])[hvidx];
        const int hx = (int)hv.x, hy = (int)hv.y, hz = (int)hv.z, hw = (int)hv.w;

        // prefetch next-step recurrent noise (the real HBM stream)
        float rn_n = 0.0f;
        if (!half) rn_n = rb[(size_t)(t + 1) * N_ + n];

        float a0 = 0.0f, a1 = 0.0f, a2 = 0.0f, a3 = 0.0f;
        if (!half) a0 = inp_c;

        DOTG(w0, 0);   DOTG(w1, 1);   DOTG(w2, 2);   DOTG(w3, 3);
        DOTG(w4, 4);   DOTG(w5, 5);   DOTG(w6, 6);   DOTG(w7, 7);

        // stream loads (consumed as G=29..31 after ~350 cy -> latency hidden)
        uint4 s0 = gload<USE_WS>(wsn, wrow_ws, 0);
        uint4 s1 = gload<USE_WS>(wsn, wrow_ws, 1);
        uint4 s2 = gload<USE_WS>(wsn, wrow_ws, 2);

        DOTG(w8, 8);   DOTG(w9, 9);   DOTG(w10, 10); DOTG(w11, 11);
        DOTG(w12, 12); DOTG(w13, 13); DOTG(w14, 14); DOTG(w15, 15);

        // LDS batch 1 (groups 20..23)
        uint4 la0 = ltail[0][tid], la1 = ltail[1][tid], la2 = ltail[2][tid], la3 = ltail[3][tid];

        DOTG(w16, 16); DOTG(w17, 17); DOTG(w18, 18); DOTG(w19, 19);
        DOTG(s0, 29);  DOTG(s1, 30);  DOTG(s2, 31);

        // LDS batch 2 (groups 24..28)
        uint4 lb0 = ltail[4][tid], lb1 = ltail[5][tid], lb2 = ltail[6][tid],
              lb3 = ltail[7][tid], lb4 = ltail[8][tid];

        DOTG(la0, 20); DOTG(la1, 21); DOTG(la2, 22); DOTG(la3, 23);
        DOTG(lb0, 24); DOTG(lb1, 25); DOTG(lb2, 26); DOTG(lb3, 27); DOTG(lb4, 28);

        const float partial = (a0 + a1) + (a2 + a3);
        if (half) pbuf[n] = partial;
        __syncthreads();

        if (!half) {
            const float pre = partial + pbuf[n];
            h = 0.8f * h + 0.2f * (fmaxf(pre, 0.0f) + rn_c);
            hbuf[(t + 1) & 1][n] = (_Float16)h;

            // next-step input drive (u/unz are tiny, same-address across the
            // half -> L1 broadcast; loaded here to keep register pressure low)
            const float2 pu0 = ubp[(t + 1) * 3 + 0], pu1 = ubp[(t + 1) * 3 + 1], pu2 = ubp[(t + 1) * 3 + 2];
            const float2 pn0 = nbp[(t + 1) * 3 + 0], pn1 = nbp[(t + 1) * 3 + 1], pn2 = nbp[(t + 1) * 3 + 2];
            float inp_n = br;
            inp_n = fmaf(win0, fmaf(NS, pn0.x, pu0.x), inp_n);
            inp_n = fmaf(win1, fmaf(NS, pn0.y, pu0.y), inp_n);
            inp_n = fmaf(win2, fmaf(NS, pn1.x, pu1.x), inp_n);
            inp_n = fmaf(win3, fmaf(NS, pn1.y, pu1.y), inp_n);
            inp_n = fmaf(win4, fmaf(NS, pn2.x, pu2.x), inp_n);
            inp_n = fmaf(win5, fmaf(NS, pn2.y, pu2.y), inp_n);
            inp_c = inp_n;
            rn_c  = rn_n;
        }
        __syncthreads();
    }
    if (!half) ob[(size_t)(T_ - 1) * N_ + n] = h;  // states[511]
}

extern "C" void kernel_launch(void* const* d_in, const int* in_sizes, int n_in,
                              void* d_out, int out_size, void* d_ws, size_t ws_size,
                              hipStream_t stream) {
    const float* u    = (const float*)d_in[0];
    const float* unz  = (const float*)d_in[1];
    const float* rnz  = (const float*)d_in[2];
    const float* Wrec = (const float*)d_in[3];
    const float* brec = (const float*)d_in[4];
    const float* Win  = (const float*)d_in[5];
    float* out = (float*)d_out;

    const size_t ws_need = (size_t)HWS * TPB * sizeof(uint4);  // 49152 B
    if (ws_size >= ws_need) {
        uint4* ws = (uint4*)d_ws;
        prep_tail_kernel<<<(HWS * TPB + 255) / 256, 256, 0, stream>>>(Wrec, ws);
        rnn_scan_kernel<true><<<dim3(B_), dim3(TPB), 0, stream>>>(
            u, unz, rnz, Wrec, brec, Win, ws, out);
    } else {
        rnn_scan_kernel<false><<<dim3(B_), dim3(TPB), 0, stream>>>(
            u, unz, rnz, Wrec, brec, Win, nullptr, out);
    }
}